// Round 8
// baseline (449.980 us; speedup 1.0000x reference)
//
#include <hip/hip_runtime.h>

// Problem constants (fixed by reference)
#define NN   20000
#define RR   11
#define BB   8
#define IND  300
#define OUTD 256
#define EE   640000
#define RN   (RR * NN)      // 220000 buckets, key = rel*N + src
#define NSCAN_BLOCKS 215    // ceil(220000 / 1024)
// K partitioning: 4 planes of 76 (pad to 80 = 5 MFMA k-steps)
#define PLU  760000u        // uints per f2u plane (20000 * 38)
#define WTU  112640u        // uints per wt plane (11*256*40)
#define SBU  42             // sbf row stride in uints (84 bf16; 2-way banks = free)
#define PPL  5120000u       // floats per P plane (20000*256)
#define FB   5938           // k_prep blocks: feat convert (1,520,000 uint2 items)
#define WB   44             // k_prep blocks: wt tiles (11 r x 4 o-tiles)
#define HB   215            // k_prep blocks: hist zero

typedef short bf16x8 __attribute__((ext_vector_type(8)));
typedef float f32x16 __attribute__((ext_vector_type(16)));

union UA { bf16x8 v; uint2 d[2]; };
union UB { bf16x8 v; uint4 q; };

__device__ inline unsigned short f2bf(float f) {
    union { float f; unsigned u; } x;
    x.f = f;
    unsigned u = x.u;
    u += 0x7fffu + ((u >> 16) & 1u);   // round-to-nearest-even
    return (unsigned short)(u >> 16);
}
__device__ inline float bflo(unsigned p) { return __uint_as_float(p << 16); }
__device__ inline float bfhi(unsigned p) { return __uint_as_float(p & 0xFFFF0000u); }
__device__ inline unsigned packbf(float x, float y) {
    return (unsigned)f2bf(x) | ((unsigned)f2bf(y) << 16);
}

// ---- fused prep: feat->bf16 K-planes | wt K-plane tiles | hist zero
__global__ __launch_bounds__(256) void k_prep(const float* __restrict__ feat,
                                              const float* __restrict__ comps,
                                              const float* __restrict__ bases,
                                              unsigned* __restrict__ f2u,
                                              unsigned* __restrict__ wtu,
                                              unsigned* __restrict__ hist) {
    __shared__ unsigned short ld[304 * 65];   // wt tile (k x o), pad 65 -> conflict-free
    const int b = blockIdx.x, tid = threadIdx.x;

    if (b < FB) {
        // f2u[kq][d][38 uints]: plane kq holds bf16 pairs for k in [76kq, 76kq+76)
        const unsigned t = b * 256u + (unsigned)tid;
        if (t < 1520000u) {
            const unsigned d  = t / 76u, rem = t - d * 76u;
            const unsigned kq = rem / 19u, w2 = rem - kq * 19u;
            const unsigned k  = kq * 76u + w2 * 4u;
            uint2 o; o.x = 0u; o.y = 0u;
            if (k < 300u) {
                const float4 x = *(const float4*)(feat + (size_t)d * IND + k);
                o.x = packbf(x.x, x.y);
                o.y = packbf(x.z, x.w);
            }
            *(uint2*)(f2u + (size_t)kq * PLU + d * 38u + w2 * 2u) = o;
        }
        return;
    }
    if (b < FB + WB) {
        // wt[kq][r][o][40 uints]: coalesced bases reads, LDS transpose, plane writes
        const int w  = b - FB;               // 0..43
        const int r  = w >> 2, o0 = (w & 3) * 64;
        const int o4 = tid & 63, kq4 = tid >> 6;    // kq4 0..3
        float cw[BB];
#pragma unroll
        for (int bb = 0; bb < BB; ++bb) cw[bb] = comps[r * BB + bb];
        for (int ks = 0; ks < 76; ++ks) {
            const int k = ks * 4 + kq4;
            float acc = 0.f;
            if (k < IND) {
#pragma unroll
                for (int bb = 0; bb < BB; ++bb)
                    acc += cw[bb] * bases[((size_t)bb * IND + k) * OUTD + o0 + o4];
            }
            ld[k * 65 + o4] = f2bf(acc);
        }
        __syncthreads();
        for (int j = tid; j < 64 * 160; j += 256) {
            const int oo = j / 160, rem = j - oo * 160;
            const int kq = rem / 40, ku = rem - kq * 40;
            unsigned val = 0u;
            if (ku < 38) {
                const int gk = kq * 76 + 2 * ku;
                val = (unsigned)ld[gk * 65 + oo] | ((unsigned)ld[(gk + 1) * 65 + oo] << 16);
            }
            wtu[(size_t)kq * WTU + ((size_t)(r * OUTD + o0 + oo)) * 40u + ku] = val;
        }
        return;
    }
    // hist zero
    const unsigned base = (unsigned)(b - FB - WB) * 1024u + (unsigned)tid;
#pragma unroll
    for (int i = 0; i < 4; ++i) {
        const unsigned idx = base + i * 256u;
        if (idx < RN) hist[idx] = 0u;
    }
}

// ---------------------------------------------------------------- histogram
__global__ __launch_bounds__(256) void k_hist(const int* __restrict__ esrc,
                                              const int* __restrict__ erel,
                                              unsigned* __restrict__ hist) {
    const int e = blockIdx.x * 256 + threadIdx.x;           // exactly 640000
    const unsigned key = (unsigned)erel[e] * NN + (unsigned)esrc[e];
    atomicAdd(&hist[key], 1u);
}

// ------------------------------------------------- scan level 1 (1024/block)
__global__ __launch_bounds__(256) void k_scan1(const unsigned* __restrict__ hist,
                                               unsigned* __restrict__ off,
                                               unsigned* __restrict__ bsum) {
    __shared__ unsigned sc[256];
    const int tid = threadIdx.x;
    const unsigned base = blockIdx.x * 1024u + (unsigned)tid * 4u;
    unsigned v0 = (base + 0 < RN) ? hist[base + 0] : 0u;
    unsigned v1 = (base + 1 < RN) ? hist[base + 1] : 0u;
    unsigned v2 = (base + 2 < RN) ? hist[base + 2] : 0u;
    unsigned v3 = (base + 3 < RN) ? hist[base + 3] : 0u;
    const unsigned s = v0 + v1 + v2 + v3;
    sc[tid] = s;
    __syncthreads();
    for (int d = 1; d < 256; d <<= 1) {
        unsigned t = (tid >= d) ? sc[tid - d] : 0u;
        __syncthreads();
        sc[tid] += t;
        __syncthreads();
    }
    if (tid == 255) bsum[blockIdx.x] = sc[255];
    unsigned run = sc[tid] - s;                              // exclusive
    if (base + 0 < RN) off[base + 0] = run; run += v0;
    if (base + 1 < RN) off[base + 1] = run; run += v1;
    if (base + 2 < RN) off[base + 2] = run; run += v2;
    if (base + 3 < RN) off[base + 3] = run;
}

// ------------- scan levels 2+3 fused: every block re-scans bsum (tiny, L2)
__global__ __launch_bounds__(256) void k_scan23(unsigned* __restrict__ off,
                                                unsigned* __restrict__ off2,
                                                const unsigned* __restrict__ bsum) {
    __shared__ unsigned sb[256];
    const int tid = threadIdx.x;
    if (tid < 64) {
        unsigned v[4]; unsigned tot = 0;
#pragma unroll
        for (int i = 0; i < 4; ++i) {
            const int idx = tid * 4 + i;
            v[i] = (idx < NSCAN_BLOCKS) ? bsum[idx] : 0u;
            tot += v[i];
        }
        unsigned sc = tot;
        for (int d = 1; d < 64; d <<= 1) {
            unsigned t = __shfl_up(sc, d, 64);
            if (tid >= d) sc += t;
        }
        unsigned run = sc - tot;
#pragma unroll
        for (int i = 0; i < 4; ++i) {
            sb[tid * 4 + i] = run;
            run += v[i];
        }
    }
    __syncthreads();
    const unsigned idx = blockIdx.x * 256u + (unsigned)tid;
    if (idx < RN) {
        const unsigned v = off[idx] + sb[idx >> 10];
        off[idx]  = v;
        off2[idx] = v;
    }
    if (idx == 0) off[RN] = EE;
}

// ------------------------------------------------------- counting-sort scatter
__global__ __launch_bounds__(256) void k_scatter(const int* __restrict__ esrc,
                                                 const int* __restrict__ erel,
                                                 const int* __restrict__ edst,
                                                 unsigned* __restrict__ off2,
                                                 unsigned* __restrict__ ssd) {
    const int e = blockIdx.x * 256 + threadIdx.x;           // exactly 640000
    const unsigned key = (unsigned)erel[e] * NN + (unsigned)esrc[e];
    const unsigned p = atomicAdd(&off2[key], 1u);
    ssd[p] = (unsigned)edst[e];                              // dst only; src = bucket
}

// ---------------------------------------------------------------- fused main
// grid = tile*4 + kq (2500 blocks): kq->XCD pinning keeps the 3 MB K-plane
// L2-resident (R6/R7 verified: FETCH 165->52 MB). R8: FLAT-EDGE gather —
// per (wave, rel) the 4 node-groups' edges are one contiguous run (mean 11.6,
// <=64 in practice); iterate e=0..total-1 so every iteration consumes one
// REAL edge (R7's predicated round-robin burned ~57 VALU slots/edge-visit on
// masked-off bodies -> 49% VALUBusy). Group boundaries are wave-uniform
// events that flush the 2-reg accumulator to the LDS A-row. Depth-4 rotating
// prefetch (4 VGPRs) keeps 4 L2 loads in flight. Register-lean by design
// (R5 lesson: stay under the (512,8) 64-reg cap).
template<int USEP>
__global__ __launch_bounds__(512, 8) void k_main(const unsigned* __restrict__ f2u,
                                                 const unsigned* __restrict__ offs,
                                                 const unsigned* __restrict__ ssd,
                                                 const unsigned* __restrict__ wtu,
                                                 float* __restrict__ out,
                                                 float* __restrict__ P) {
    __shared__ unsigned sbu[2][32 * SBU];     // A tile: 32 rows x 42 uints, dbuf
    __shared__ unsigned soffs[RR * 33];

    const int tid  = threadIdx.x;
    const int wave = tid >> 6;
    const int lane = tid & 63;
    const int row  = lane & 31;
    const int q    = lane >> 5;
    const int kq   = blockIdx.x & 3;
    const int tile = blockIdx.x >> 2;
    const int n0   = tile * 32;
    const int o0   = wave * 32;
    const unsigned vcl = (unsigned)(lane < 38 ? lane : 37);  // clamped col

    const unsigned* fp = f2u + (size_t)kq * PLU;    // this block's K-plane
    const unsigned* wp = wtu + (size_t)kq * WTU;

    if (tid < RR * 33) {
        const int r = tid / 33, j = tid - r * 33;
        soffs[tid] = offs[r * NN + n0 + j];
    }

    f32x16 acc;
#pragma unroll
    for (int i = 0; i < 16; ++i) acc[i] = 0.f;

    __syncthreads();

    int buf = 0;
    for (int r = 0; r < RR; ++r) {
        const unsigned* so = soffs + r * 33 + wave * 4;
        const unsigned s0    = __builtin_amdgcn_readfirstlane((int)so[0]);
        const unsigned b1    = __builtin_amdgcn_readfirstlane((int)so[1]) - s0;
        const unsigned b2    = __builtin_amdgcn_readfirstlane((int)so[2]) - s0;
        const unsigned b3    = __builtin_amdgcn_readfirstlane((int)so[3]) - s0;
        const unsigned total = __builtin_amdgcn_readfirstlane((int)so[4]) - s0;

        float fa0 = 0.f, fa1 = 0.f;
        int g = 0;                 // current node-group being accumulated
        unsigned gs = 0;           // start offset of current group

        // flush current group's accumulated row -> sbu A-row (nb = group end)
#define FLUSH(nb)                                                             \
        {                                                                     \
            const unsigned c = (nb) - gs;                                     \
            const float inv = c ? 1.0f / (float)c : 0.f;                      \
            if (lane < 40)                                                    \
                sbu[buf][(wave * 4 + g) * SBU + lane] =                       \
                    (lane < 38) ? packbf(fa0 * inv, fa1 * inv) : 0u;          \
            fa0 = 0.f; fa1 = 0.f;                                             \
            gs = (nb);                                                        \
            ++g;                                                              \
        }
#define BND(gg) ((gg) == 0 ? b1 : (gg) == 1 ? b2 : (gg) == 2 ? b3 : total)

        if (total <= 64u) {
            // one coalesced 64-wide window covers the whole run
            const unsigned win = ((unsigned)lane < total) ? ssd[s0 + (unsigned)lane] : 0u;
            unsigned nb = BND(0);
            unsigned p0 = 0u, p1 = 0u, p2 = 0u, p3 = 0u;   // depth-4 prefetch ring
            if (total > 0) p0 = fp[(size_t)(unsigned)__builtin_amdgcn_readlane((int)win, 0) * 38u + vcl];
            if (total > 1) p1 = fp[(size_t)(unsigned)__builtin_amdgcn_readlane((int)win, 1) * 38u + vcl];
            if (total > 2) p2 = fp[(size_t)(unsigned)__builtin_amdgcn_readlane((int)win, 2) * 38u + vcl];
            if (total > 3) p3 = fp[(size_t)(unsigned)__builtin_amdgcn_readlane((int)win, 3) * 38u + vcl];
            for (unsigned e = 0; e < total; ++e) {
                while (e == nb) {                        // wave-uniform boundary
                    FLUSH(nb);
                    nb = (g < 4) ? BND(g) : 0xFFFFFFFFu;
                }
                unsigned v;
                const unsigned slot = e & 3u;
                if (slot == 0u) v = p0; else if (slot == 1u) v = p1;
                else if (slot == 2u) v = p2; else v = p3;
                const unsigned en = e + 4u;
                if (en < total) {
                    const unsigned vn =
                        fp[(size_t)(unsigned)__builtin_amdgcn_readlane((int)win, (int)en) * 38u + vcl];
                    if (slot == 0u) p0 = vn; else if (slot == 1u) p1 = vn;
                    else if (slot == 2u) p2 = vn; else p3 = vn;
                }
                fa0 += bflo(v); fa1 += bfhi(v);
            }
            while (g < 4) {                              // tail + empty groups
                const unsigned nb2 = BND(g);
                FLUSH(nb2);
            }
        } else {
            // rare overflow: serial depth-1 per group
            while (g < 4) {
                const unsigned ge = BND(g);
                for (unsigned e = s0 + gs; e < s0 + ge; ++e) {
                    const unsigned v = fp[(size_t)ssd[e] * 38u + vcl];
                    fa0 += bflo(v); fa1 += bfhi(v);
                }
                FLUSH(ge);
            }
        }
#undef FLUSH
#undef BND
        __syncthreads();

        // --- MFMA: C[32 nodes x 32 outs] += A[32 x 80] * B[80 x 32]
        const unsigned short* wb =
            (const unsigned short*)(wp + (size_t)(r * OUTD + o0 + row) * 40u) + 8 * q;
        const unsigned short* ab = (const unsigned short*)(sbu[buf] + row * SBU) + 8 * q;
#pragma unroll
        for (int ks = 0; ks < 5; ++ks) {
            UA a; UB b;
            a.d[0] = *(const uint2*)(ab + 16 * ks);
            a.d[1] = *(const uint2*)(ab + 16 * ks + 4);
            b.q    = *(const uint4*)(wb + 16 * ks);
            acc = __builtin_amdgcn_mfma_f32_32x32x16_bf16(a.v, b.v, acc, 0, 0, 0);
        }
        buf ^= 1;   // next gather writes the other buffer; no post-MFMA barrier
    }

    // --- epilogue: C/D layout col=lane&31 (=o), row=(reg&3)+8*(reg>>2)+4*q (=node)
    const int o = o0 + row;
    if (USEP) {
        float* op = P + (size_t)kq * PPL;
#pragma unroll
        for (int reg = 0; reg < 16; ++reg) {
            const int node = (reg & 3) + 8 * (reg >> 2) + 4 * q;
            op[(size_t)(n0 + node) * OUTD + o] = acc[reg];
        }
    } else {
#pragma unroll
        for (int reg = 0; reg < 16; ++reg) {
            const int node = (reg & 3) + 8 * (reg >> 2) + 4 * q;
            atomicAdd(&out[(size_t)(n0 + node) * OUTD + o], acc[reg]);
        }
    }
}

// ---------------- out = bias (atomic-fallback init), or out = sum(P) + bias
__global__ __launch_bounds__(256) void k_initout(float* __restrict__ out,
                                                 const float* __restrict__ bias) {
    const unsigned i = blockIdx.x * 256u + threadIdx.x;     // 1,280,000 float4
    ((float4*)out)[i] = ((const float4*)bias)[i & 63u];
}

__global__ __launch_bounds__(256) void k_add(float* __restrict__ out,
                                             const float* __restrict__ P,
                                             const float* __restrict__ bias) {
    const unsigned i = blockIdx.x * 256u + threadIdx.x;     // 1,280,000 float4
    const float4 p0 = ((const float4*)(P))[i];
    const float4 p1 = ((const float4*)(P + PPL))[i];
    const float4 p2 = ((const float4*)(P + 2 * (size_t)PPL))[i];
    const float4 p3 = ((const float4*)(P + 3 * (size_t)PPL))[i];
    const float4 bv = ((const float4*)bias)[i & 63u];
    float4 o;
    o.x = p0.x + p1.x + p2.x + p3.x + bv.x;
    o.y = p0.y + p1.y + p2.y + p3.y + bv.y;
    o.z = p0.z + p1.z + p2.z + p3.z + bv.z;
    o.w = p0.w + p1.w + p2.w + p3.w + bv.w;
    ((float4*)out)[i] = o;
}

extern "C" void kernel_launch(void* const* d_in, const int* in_sizes, int n_in,
                              void* d_out, int out_size, void* d_ws, size_t ws_size,
                              hipStream_t stream) {
    const float* feat  = (const float*)d_in[0];
    const float* comps = (const float*)d_in[1];
    const float* bases = (const float*)d_in[2];
    const float* bias  = (const float*)d_in[3];
    const int*   esrc  = (const int*)d_in[4];
    const int*   erel  = (const int*)d_in[5];
    const int*   edst  = (const int*)d_in[6];
    float* out = (float*)d_out;

    char* ws = (char*)d_ws;
    // ws layout (bytes):
    unsigned* wtu  = (unsigned*)(ws + 0);          //  1,802,240 (4 planes x 450,560)
    unsigned* hist = (unsigned*)(ws + 1802240);    //    880,000
    unsigned* off  = (unsigned*)(ws + 2682240);    //    880,064 (incl pad)
    unsigned* off2 = (unsigned*)(ws + 3562304);    //    880,000
    unsigned* bsum = (unsigned*)(ws + 4442304);    //      1,024
    unsigned* ssd  = (unsigned*)(ws + 4443328);    //  2,560,000
    unsigned* f2u  = (unsigned*)(ws + 7003328);    // 12,160,000 -> 19,163,328
    float*    P    = (float*)(ws + 19163328);      // 81,920,000 -> 101,083,328

    const bool usep = ws_size >= (size_t)101083328;  // host-uniform every call

    hipLaunchKernelGGL(k_prep,    dim3(FB + WB + HB), dim3(256), 0, stream,
                       feat, comps, bases, f2u, wtu, hist);
    hipLaunchKernelGGL(k_hist,    dim3(2500), dim3(256), 0, stream, esrc, erel, hist);
    hipLaunchKernelGGL(k_scan1,   dim3(NSCAN_BLOCKS), dim3(256), 0, stream, hist, off, bsum);
    hipLaunchKernelGGL(k_scan23,  dim3(860),  dim3(256), 0, stream, off, off2, bsum);
    hipLaunchKernelGGL(k_scatter, dim3(2500), dim3(256), 0, stream, esrc, erel, edst, off2, ssd);
    if (usep) {
        hipLaunchKernelGGL((k_main<1>), dim3(2500), dim3(512), 0, stream,
                           f2u, off, ssd, wtu, out, P);
        hipLaunchKernelGGL(k_add, dim3(5000), dim3(256), 0, stream, out, P, bias);
    } else {
        hipLaunchKernelGGL(k_initout, dim3(5000), dim3(256), 0, stream, out, bias);
        hipLaunchKernelGGL((k_main<0>), dim3(2500), dim3(512), 0, stream,
                           f2u, off, ssd, wtu, out, P);
    }

    (void)in_sizes; (void)n_in; (void)out_size; (void)ws_size;
}